// Round 4
// baseline (301.213 us; speedup 1.0000x reference)
//
#include <hip/hip_runtime.h>

typedef _Float16 half_t;
typedef _Float16 half8 __attribute__((ext_vector_type(8)));
typedef float f32x4 __attribute__((ext_vector_type(4)));

#define NELEM 16384

// ---------------------------------------------------------------------------
// Fused dense layer via 16x16x32 f16 MFMA. ks-outer / mt-inner: MT independent
// accumulator chains to cover MFMA latency.
//   A : LDS fp16 row-major, stride sA halves. B : global pre-swizzled frags
//   [split][ks][nt][lane][8], split0=hi(fp16 w), split1=lo(fp16(w-hi)).
//   Layouts (verified): A[m=lane&15][k=quad*8+j], B[k][n=lane&15],
//                       D[row=quad*4+r][col=lane&15].
// EPI: 0=fp16 store (opt relu), 1=fp32 store col<C, 2=logits col0, 3=gp rows0-3.
// INIT: 1 = add gp[row/20][col].  Tiles nt in [NT,NTZ) write zeros (K-pad).
// ---------------------------------------------------------------------------
template<int KS, int MT, int EPI, int INIT>
__device__ __forceinline__ void dense_mfma(
    const half_t* inA, int sA, void* outP, int sO,
    const half_t* __restrict__ wf, const float* __restrict__ bias,
    const float* gp, float* lbuf, float extra,
    int NT, int NTZ, int C, bool relu, int tid)
{
    const int lane = tid & 63, wave = tid >> 6;
    const int m = lane & 15, quad = lane >> 4;
    for (int nt = wave; nt < NTZ; nt += 4) {
        const int col = nt * 16 + m;
        const bool live = nt < NT;
        f32x4 acc[MT];
        #pragma unroll
        for (int t = 0; t < MT; ++t) acc[t] = f32x4{0.f,0.f,0.f,0.f};
        float bv = 0.f;
        if (live) {
            half8 bh[KS], bl[KS];
            #pragma unroll
            for (int ks = 0; ks < KS; ++ks) {
                bh[ks] = *(const half8*)(wf + ((size_t)(ks*NT + nt)*64 + lane)*8);
                bl[ks] = *(const half8*)(wf + ((size_t)((KS+ks)*NT + nt)*64 + lane)*8);
            }
            if (bias && col < C) bv = bias[col];
            #pragma unroll
            for (int ks = 0; ks < KS; ++ks) {
                half8 a[MT];
                #pragma unroll
                for (int t = 0; t < MT; ++t)
                    a[t] = *(const half8*)(inA + (t*16 + m)*sA + quad*8 + ks*32);
                #pragma unroll
                for (int t = 0; t < MT; ++t)
                    acc[t] = __builtin_amdgcn_mfma_f32_16x16x32_f16(a[t], bh[ks], acc[t], 0,0,0);
                #pragma unroll
                for (int t = 0; t < MT; ++t)
                    acc[t] = __builtin_amdgcn_mfma_f32_16x16x32_f16(a[t], bl[ks], acc[t], 0,0,0);
            }
        }
        #pragma unroll
        for (int t = 0; t < MT; ++t) {
            #pragma unroll
            for (int r = 0; r < 4; ++r) {
                const int row = t*16 + quad*4 + r;
                float v = acc[t][r] + bv;
                if (INIT == 1) { if (live) v += gp[(row/20)*112 + col]; }
                if (relu) v = fmaxf(v, 0.f);
                if (EPI == 0) {
                    ((half_t*)outP)[row*sO + col] = (half_t)v;
                } else if (EPI == 1) {
                    if (col < C) ((float*)outP)[row*sO + col] = v;
                } else if (EPI == 2) {
                    if (m == 0) lbuf[row] = acc[t][r] + extra;
                } else {
                    if (quad == 0) ((float*)outP)[r*sO + col] = acc[t][r];
                }
            }
        }
    }
}

// ---------------------------------------------------------------------------
// Prep: build split-fp16 weight fragments in ws.
// ---------------------------------------------------------------------------
struct PrepDesc { const float* w; half_t* out; int K, C, KS, NT, toff; };
struct PrepArgs { PrepDesc d[11]; };

__global__ __launch_bounds__(64) void k_prep(PrepArgs a) {
    const int blk = blockIdx.x, lane = threadIdx.x;
    int li = 0;
    #pragma unroll
    for (int i = 1; i < 11; ++i) if (blk >= a.d[i].toff) li = i;
    const PrepDesc d = a.d[li];
    const int t = blk - d.toff;
    const int kn = d.KS * d.NT;
    const int split = t / kn;
    const int rem = t - split * kn;
    const int ks = rem / d.NT, nt = rem - (rem / d.NT) * d.NT;
    const int c = nt*16 + (lane & 15);
    half_t* o = d.out + ((size_t)(split*d.KS + ks)*d.NT + nt)*512 + lane*8;
    #pragma unroll
    for (int j = 0; j < 8; ++j) {
        const int k = ks*32 + (lane >> 4)*8 + j;
        float v = (k < d.K && c < d.C) ? d.w[(size_t)k*d.C + c] : 0.f;
        half_t hi = (half_t)v;
        half_t lo = (half_t)(v - (float)hi);
        o[j] = split ? lo : hi;
    }
}

// ---------------------------------------------------------------------------
// k_main: 4 elements (80 rows) per block. Entire network fused, incl. head.
// ---------------------------------------------------------------------------
__global__ __launch_bounds__(256, 2) void k_main(
    const float* __restrict__ state,
    const half_t* __restrict__ wfrag,
    const float* __restrict__ m1b0, const float* __restrict__ m1b1,
    const float* __restrict__ m2b0, const float* __restrict__ m2b1,
    const float* __restrict__ ab0, const float* __restrict__ ab1,
    const float* __restrict__ ab2,
    const float* __restrict__ m3b0, const float* __restrict__ m3b1,
    const float* __restrict__ m3b2,
    const float* __restrict__ m3w3, const float* __restrict__ m3b3,
    float* __restrict__ out)
{
    __shared__ __align__(16) half_t bufA[80*168];
    __shared__ __align__(16) half_t bufB[80*168];
    __shared__ __align__(16) float  fbuf[80*56];
    __shared__ __align__(16) half_t gbuf[16*136];   // g early; jbuf (16x72) late
    __shared__ __align__(16) float  gpbuf[4*112];
    __shared__ float lbuf[80];

    const int tid = threadIdx.x;
    const int blk = blockIdx.x;

    for (int i = tid; i < 80*168; i += 256) bufA[i] = (half_t)0.f;
    for (int i = tid; i < 16*136; i += 256) gbuf[i] = (half_t)0.f;
    __syncthreads();
    for (int u = tid; u < 80*13; u += 256) {
        const int r = u / 13, d = u - r*13;
        bufA[r*168 + d] = (half_t)state[(size_t)(blk*80 + r)*13 + d];
    }
    __syncthreads();

    const half_t* wfL0 = wfrag;
    const half_t* wfL1 = wfL0 + 10240;
    const half_t* wfL2 = wfL1 + 35840;
    const half_t* wfL3 = wfL2 + 28672;
    const half_t* wfL4 = wfL3 + 16384;
    const half_t* wfL5 = wfL4 + 28672;
    const half_t* wfL6 = wfL5 + 28672;
    const half_t* wfL7 = wfL6 + 28672;
    const half_t* wfL8 = wfL7 + 4096;
    const half_t* wfL9 = wfL8 + 20480;
    const half_t* wfL10 = wfL9 + 35840;

    // h1 = relu(x @ m1w0 + b)
    dense_mfma<1,5,0,0>(bufA,168, bufB,168, wfL0, m1b0, nullptr,nullptr,0.f, 10,10,150,true, tid);
    __syncthreads();
    // h = relu(h1 @ m1w1 + b)
    dense_mfma<5,5,0,0>(bufB,168, bufA,168, wfL1, m1b1, nullptr,nullptr,0.f, 7,8,100,true, tid);
    __syncthreads();
    // fh = relu(h @ m2w0 + b);  g = mean_n h
    dense_mfma<4,5,0,0>(bufA,168, bufB,168, wfL2, m2b0, nullptr,nullptr,0.f, 7,8,100,true, tid);
    for (int u = tid; u < 400; u += 256) {
        const int e = u / 100, c = u - e*100;
        float s = 0.f;
        #pragma unroll
        for (int n = 0; n < 20; ++n) s += (float)bufA[(e*20+n)*168 + c];
        gbuf[e*136 + c] = (half_t)(s * 0.05f);
    }
    __syncthreads();
    // f = fh @ m2w1 + b (fp32);  gp = g @ aw0[100:]
    dense_mfma<4,5,1,0>(bufB,168, fbuf,56, wfL3, m2b1, nullptr,nullptr,0.f, 4,4,50,false, tid);
    dense_mfma<4,1,3,0>(gbuf,136, gpbuf,112, wfL5, nullptr, nullptr,nullptr,0.f, 7,7,100,false, tid);
    __syncthreads();
    // a1 = relu(h @ aw0[:100] + gp + ab0)
    dense_mfma<4,5,0,1>(bufA,168, bufB,168, wfL4, ab0, gpbuf,nullptr,0.f, 7,8,100,true, tid);
    __syncthreads();
    // a2 = relu(a1 @ aw1 + ab1)
    dense_mfma<4,5,0,0>(bufB,168, bufA,168, wfL6, ab1, nullptr,nullptr,0.f, 7,8,100,true, tid);
    __syncthreads();
    // logits = a2 @ aw2 + ab2 ; zero jbuf (gbuf region, dead) while most waves idle
    {
        const float ab2v = ab2[0];
        dense_mfma<4,5,2,0>(bufA,168, nullptr,0, wfL7, nullptr, nullptr,lbuf,ab2v, 1,1,1,false, tid);
    }
    for (int i = tid; i < 16*72; i += 256) gbuf[i] = (half_t)0.f;
    __syncthreads();

    // weighted + self -> jbuf rows 0..3 (fp16), cols 0..55; rest stays zero
    half_t* jbuf = gbuf;
    for (int u = tid; u < 224; u += 256) {
        if (u < 200) {
            const int e = u / 50, j = u - e*50;
            float s = 0.f;
            #pragma unroll
            for (int n = 0; n < 20; ++n)
                s = fmaf(fbuf[(e*20+n)*56 + j], lbuf[e*20+n], s);
            jbuf[e*72 + 6 + j] = (half_t)s;
        } else {
            const int u2 = u - 200, e = u2 / 6, d = u2 - (u2/6)*6;
            jbuf[e*72 + d] = (half_t)state[(size_t)(blk*4+e)*260 + d];
        }
    }
    __syncthreads();

    // head: v1 = relu(joint @ m3w0 + b0)   (16 rows: 4 real + 12 pad)
    dense_mfma<2,1,0,0>(jbuf,72, bufB,168, wfL8, m3b0, nullptr,nullptr,0.f, 10,10,150,true, tid);
    __syncthreads();
    // v2 = relu(v1 @ m3w1 + b1)
    dense_mfma<5,1,0,0>(bufB,168, bufA,168, wfL9, m3b1, nullptr,nullptr,0.f, 7,8,100,true, tid);
    __syncthreads();
    // v3 = relu(v2 @ m3w2 + b2)
    dense_mfma<4,1,0,0>(bufA,168, bufB,168, wfL10, m3b2, nullptr,nullptr,0.f, 7,7,100,true, tid);
    __syncthreads();

    // out[e] = v3[e] . m3w3 + b3  (wave = element)
    {
        const int wv = tid >> 6, lane = tid & 63;
        float s = (float)bufB[wv*168 + lane] * m3w3[lane];
        if (lane < 36) s += (float)bufB[wv*168 + 64 + lane] * m3w3[64 + lane];
        #pragma unroll
        for (int off = 32; off > 0; off >>= 1)
            s += __shfl_down(s, off, 64);
        if (lane == 0) out[(size_t)blk*4 + wv] = s + m3b3[0];
    }
}

extern "C" void kernel_launch(void* const* d_in, const int* in_sizes, int n_in,
                              void* d_out, int out_size, void* d_ws, size_t ws_size,
                              hipStream_t stream) {
    const float* state = (const float*)d_in[0];
    const float* m1w0 = (const float*)d_in[1];
    const float* m1b0 = (const float*)d_in[2];
    const float* m1w1 = (const float*)d_in[3];
    const float* m1b1 = (const float*)d_in[4];
    const float* m2w0 = (const float*)d_in[5];
    const float* m2b0 = (const float*)d_in[6];
    const float* m2w1 = (const float*)d_in[7];
    const float* m2b1 = (const float*)d_in[8];
    const float* aw0  = (const float*)d_in[9];
    const float* ab0  = (const float*)d_in[10];
    const float* aw1  = (const float*)d_in[11];
    const float* ab1  = (const float*)d_in[12];
    const float* aw2  = (const float*)d_in[13];
    const float* ab2  = (const float*)d_in[14];
    const float* m3w0 = (const float*)d_in[15];
    const float* m3b0 = (const float*)d_in[16];
    const float* m3w1 = (const float*)d_in[17];
    const float* m3b1 = (const float*)d_in[18];
    const float* m3w2 = (const float*)d_in[19];
    const float* m3b2 = (const float*)d_in[20];
    const float* m3w3 = (const float*)d_in[21];
    const float* m3b3 = (const float*)d_in[22];

    half_t* wfrag = (half_t*)d_ws;   // 532 KB of fragments

    PrepArgs pa;
    int off = 0; size_t hoff = 0; int idx = 0;
    auto add = [&](const float* w, int K, int C, int KS, int NT) {
        pa.d[idx] = PrepDesc{w, wfrag + hoff, K, C, KS, NT, off};
        off += 2*KS*NT;
        hoff += (size_t)2*KS*NT*512;
        ++idx;
    };
    add(m1w0, 13, 150, 1, 10);          // L0
    add(m1w1, 150, 100, 5, 7);          // L1
    add(m2w0, 100, 100, 4, 7);          // L2
    add(m2w1, 100, 50, 4, 4);           // L3
    add(aw0, 100, 100, 4, 7);           // L4 (rows 0..99)
    add(aw0 + 100*100, 100, 100, 4, 7); // L5 (rows 100..199)
    add(aw1, 100, 100, 4, 7);           // L6
    add(aw2, 100, 1, 4, 1);             // L7
    add(m3w0, 56, 150, 2, 10);          // L8
    add(m3w1, 150, 100, 5, 7);          // L9
    add(m3w2, 100, 100, 4, 7);          // L10

    k_prep<<<off, 64, 0, stream>>>(pa);

    k_main<<<NELEM/4, 256, 0, stream>>>(state, wfrag,
        m1b0, m1b1, m2b0, m2b1, ab0, ab1, ab2,
        m3b0, m3b1, m3b2, m3w3, m3b3, (float*)d_out);
}

// Round 5
// 232.905 us; speedup vs baseline: 1.2933x; 1.2933x over previous
//
#include <hip/hip_runtime.h>

typedef _Float16 half_t;
typedef _Float16 half8 __attribute__((ext_vector_type(8)));
typedef float f32x4 __attribute__((ext_vector_type(4)));

#define NELEM 16384

// ---------------------------------------------------------------------------
// Fused dense layer via 16x16x32 f16 MFMA. Pure-fp16 weights (no hi/lo split;
// error budget verified R3: activation-rounding dominates). 8 waves, one
// nt-tile per wave per round. MT independent accumulator chains.
//   A : LDS fp16 row-major, stride sA halves. B : global pre-swizzled frags
//   [ks][nt][lane][8].
//   Layouts (verified): A[m=lane&15][k=quad*8+j], B[k][n=lane&15],
//                       D[row=quad*4+r][col=lane&15].
// EPI: 0=fp16 store (opt relu), 1=fp32 store col<C, 2=logits col0, 3=gp rows0-3.
// INIT: 1 = add gp[row/20][col].  Tiles nt in [NT,NTZ) write zeros (K-pad).
// ---------------------------------------------------------------------------
template<int KS, int MT, int EPI, int INIT>
__device__ __forceinline__ void dense_mfma(
    const half_t* inA, int sA, void* outP, int sO,
    const half_t* __restrict__ wf, const float* __restrict__ bias,
    const float* gp, float* lbuf, float extra,
    int NT, int NTZ, int C, bool relu, int tid)
{
    const int lane = tid & 63, wave = tid >> 6;
    const int m = lane & 15, quad = lane >> 4;
    for (int nt = wave; nt < NTZ; nt += 8) {
        const int col = nt * 16 + m;
        const bool live = nt < NT;
        f32x4 acc[MT];
        #pragma unroll
        for (int t = 0; t < MT; ++t) acc[t] = f32x4{0.f,0.f,0.f,0.f};
        float bv = 0.f;
        if (live) {
            half8 bh[KS];
            #pragma unroll
            for (int ks = 0; ks < KS; ++ks)
                bh[ks] = *(const half8*)(wf + ((size_t)(ks*NT + nt)*64 + lane)*8);
            if (bias && col < C) bv = bias[col];
            #pragma unroll
            for (int ks = 0; ks < KS; ++ks) {
                half8 a[MT];
                #pragma unroll
                for (int t = 0; t < MT; ++t)
                    a[t] = *(const half8*)(inA + (t*16 + m)*sA + quad*8 + ks*32);
                #pragma unroll
                for (int t = 0; t < MT; ++t)
                    acc[t] = __builtin_amdgcn_mfma_f32_16x16x32_f16(a[t], bh[ks], acc[t], 0,0,0);
            }
        }
        #pragma unroll
        for (int t = 0; t < MT; ++t) {
            #pragma unroll
            for (int r = 0; r < 4; ++r) {
                const int row = t*16 + quad*4 + r;
                float v = acc[t][r] + bv;
                if (INIT == 1) { if (live) v += gp[(row/20)*112 + col]; }
                if (relu) v = fmaxf(v, 0.f);
                if (EPI == 0) {
                    ((half_t*)outP)[row*sO + col] = (half_t)v;
                } else if (EPI == 1) {
                    if (col < C) ((float*)outP)[row*sO + col] = v;
                } else if (EPI == 2) {
                    if (m == 0) lbuf[row] = acc[t][r] + extra;
                } else {
                    if (quad == 0) ((float*)outP)[r*sO + col] = acc[t][r];
                }
            }
        }
    }
}

// ---------------------------------------------------------------------------
// Prep: build fp16 weight fragments in ws. One 16x32 tile per block.
// ---------------------------------------------------------------------------
struct PrepDesc { const float* w; half_t* out; int K, C, KS, NT, toff; };
struct PrepArgs { PrepDesc d[11]; };

__global__ __launch_bounds__(64) void k_prep(PrepArgs a) {
    const int blk = blockIdx.x, lane = threadIdx.x;
    int li = 0;
    #pragma unroll
    for (int i = 1; i < 11; ++i) if (blk >= a.d[i].toff) li = i;
    const PrepDesc d = a.d[li];
    const int t = blk - d.toff;
    const int ks = t / d.NT, nt = t - (t / d.NT) * d.NT;
    const int c = nt*16 + (lane & 15);
    half_t* o = d.out + ((size_t)(ks*d.NT + nt))*512 + lane*8;
    #pragma unroll
    for (int j = 0; j < 8; ++j) {
        const int k = ks*32 + (lane >> 4)*8 + j;
        float v = (k < d.K && c < d.C) ? d.w[(size_t)k*d.C + c] : 0.f;
        o[j] = (half_t)v;
    }
}

// ---------------------------------------------------------------------------
// k_main: 4 elements (80 rows) per block, 512 threads (8 waves).
// Entire network fused, incl. head.
// ---------------------------------------------------------------------------
__global__ __launch_bounds__(512, 4) void k_main(
    const float* __restrict__ state,
    const half_t* __restrict__ wfrag,
    const float* __restrict__ m1b0, const float* __restrict__ m1b1,
    const float* __restrict__ m2b0, const float* __restrict__ m2b1,
    const float* __restrict__ ab0, const float* __restrict__ ab1,
    const float* __restrict__ ab2,
    const float* __restrict__ m3b0, const float* __restrict__ m3b1,
    const float* __restrict__ m3b2,
    const float* __restrict__ m3w3, const float* __restrict__ m3b3,
    float* __restrict__ out)
{
    __shared__ __align__(16) half_t bufA[80*168];
    __shared__ __align__(16) half_t bufB[80*168];
    __shared__ __align__(16) float  fbuf[80*56];
    __shared__ __align__(16) half_t gbuf[16*136];   // g early; jbuf (16x72) late
    __shared__ __align__(16) float  gpbuf[4*112];
    __shared__ float lbuf[80];

    const int tid = threadIdx.x;
    const int blk = blockIdx.x;

    for (int i = tid; i < 80*168; i += 512) bufA[i] = (half_t)0.f;
    for (int i = tid; i < 16*136; i += 512) gbuf[i] = (half_t)0.f;
    __syncthreads();
    for (int u = tid; u < 80*13; u += 512) {
        const int r = u / 13, d = u - r*13;
        bufA[r*168 + d] = (half_t)state[(size_t)(blk*80 + r)*13 + d];
    }
    __syncthreads();

    const half_t* wfL0 = wfrag;
    const half_t* wfL1 = wfL0 + 5120;
    const half_t* wfL2 = wfL1 + 17920;
    const half_t* wfL3 = wfL2 + 14336;
    const half_t* wfL4 = wfL3 + 8192;
    const half_t* wfL5 = wfL4 + 14336;
    const half_t* wfL6 = wfL5 + 14336;
    const half_t* wfL7 = wfL6 + 14336;
    const half_t* wfL8 = wfL7 + 2048;
    const half_t* wfL9 = wfL8 + 10240;
    const half_t* wfL10 = wfL9 + 17920;

    // h1 = relu(x @ m1w0 + b)
    dense_mfma<1,5,0,0>(bufA,168, bufB,168, wfL0, m1b0, nullptr,nullptr,0.f, 10,10,150,true, tid);
    __syncthreads();
    // h = relu(h1 @ m1w1 + b)
    dense_mfma<5,5,0,0>(bufB,168, bufA,168, wfL1, m1b1, nullptr,nullptr,0.f, 7,8,100,true, tid);
    __syncthreads();
    // fh = relu(h @ m2w0 + b);  g = mean_n h
    dense_mfma<4,5,0,0>(bufA,168, bufB,168, wfL2, m2b0, nullptr,nullptr,0.f, 7,8,100,true, tid);
    for (int u = tid; u < 400; u += 512) {
        const int e = u / 100, c = u - e*100;
        float s = 0.f;
        #pragma unroll
        for (int n = 0; n < 20; ++n) s += (float)bufA[(e*20+n)*168 + c];
        gbuf[e*136 + c] = (half_t)(s * 0.05f);
    }
    __syncthreads();
    // f = fh @ m2w1 + b (fp32, waves 0-3);  gp = g @ aw0[100:] (waves 0-6)
    dense_mfma<4,5,1,0>(bufB,168, fbuf,56, wfL3, m2b1, nullptr,nullptr,0.f, 4,4,50,false, tid);
    dense_mfma<4,1,3,0>(gbuf,136, gpbuf,112, wfL5, nullptr, nullptr,nullptr,0.f, 7,7,100,false, tid);
    __syncthreads();
    // a1 = relu(h @ aw0[:100] + gp + ab0)
    dense_mfma<4,5,0,1>(bufA,168, bufB,168, wfL4, ab0, gpbuf,nullptr,0.f, 7,8,100,true, tid);
    __syncthreads();
    // a2 = relu(a1 @ aw1 + ab1)
    dense_mfma<4,5,0,0>(bufB,168, bufA,168, wfL6, ab1, nullptr,nullptr,0.f, 7,8,100,true, tid);
    __syncthreads();
    // logits = a2 @ aw2 + ab2 (wave 0); zero jbuf region meanwhile
    {
        const float ab2v = ab2[0];
        dense_mfma<4,5,2,0>(bufA,168, nullptr,0, wfL7, nullptr, nullptr,lbuf,ab2v, 1,1,1,false, tid);
    }
    for (int i = tid; i < 16*72; i += 512) gbuf[i] = (half_t)0.f;
    __syncthreads();

    // weighted + self -> jbuf rows 0..3 (fp16), cols 0..55; rest stays zero
    half_t* jbuf = gbuf;
    for (int u = tid; u < 224; u += 512) {
        if (u < 200) {
            const int e = u / 50, j = u - e*50;
            float s = 0.f;
            #pragma unroll
            for (int n = 0; n < 20; ++n)
                s = fmaf(fbuf[(e*20+n)*56 + j], lbuf[e*20+n], s);
            jbuf[e*72 + 6 + j] = (half_t)s;
        } else {
            const int u2 = u - 200, e = u2 / 6, d = u2 - (u2/6)*6;
            jbuf[e*72 + d] = (half_t)state[(size_t)(blk*4+e)*260 + d];
        }
    }
    __syncthreads();

    // head: v1 = relu(joint @ m3w0 + b0)   (16 rows: 4 real + 12 pad)
    dense_mfma<2,1,0,0>(jbuf,72, bufB,168, wfL8, m3b0, nullptr,nullptr,0.f, 10,10,150,true, tid);
    __syncthreads();
    // v2 = relu(v1 @ m3w1 + b1)
    dense_mfma<5,1,0,0>(bufB,168, bufA,168, wfL9, m3b1, nullptr,nullptr,0.f, 7,8,100,true, tid);
    __syncthreads();
    // v3 = relu(v2 @ m3w2 + b2)
    dense_mfma<4,1,0,0>(bufA,168, bufB,168, wfL10, m3b2, nullptr,nullptr,0.f, 7,7,100,true, tid);
    __syncthreads();

    // out[e] = v3[e] . m3w3 + b3  (wave = element; waves 4-7 idle)
    {
        const int wv = tid >> 6, lane = tid & 63;
        if (wv < 4) {
            float s = (float)bufB[wv*168 + lane] * m3w3[lane];
            if (lane < 36) s += (float)bufB[wv*168 + 64 + lane] * m3w3[64 + lane];
            #pragma unroll
            for (int off = 32; off > 0; off >>= 1)
                s += __shfl_down(s, off, 64);
            if (lane == 0) out[(size_t)blk*4 + wv] = s + m3b3[0];
        }
    }
}

extern "C" void kernel_launch(void* const* d_in, const int* in_sizes, int n_in,
                              void* d_out, int out_size, void* d_ws, size_t ws_size,
                              hipStream_t stream) {
    const float* state = (const float*)d_in[0];
    const float* m1w0 = (const float*)d_in[1];
    const float* m1b0 = (const float*)d_in[2];
    const float* m1w1 = (const float*)d_in[3];
    const float* m1b1 = (const float*)d_in[4];
    const float* m2w0 = (const float*)d_in[5];
    const float* m2b0 = (const float*)d_in[6];
    const float* m2w1 = (const float*)d_in[7];
    const float* m2b1 = (const float*)d_in[8];
    const float* aw0  = (const float*)d_in[9];
    const float* ab0  = (const float*)d_in[10];
    const float* aw1  = (const float*)d_in[11];
    const float* ab1  = (const float*)d_in[12];
    const float* aw2  = (const float*)d_in[13];
    const float* ab2  = (const float*)d_in[14];
    const float* m3w0 = (const float*)d_in[15];
    const float* m3b0 = (const float*)d_in[16];
    const float* m3w1 = (const float*)d_in[17];
    const float* m3b1 = (const float*)d_in[18];
    const float* m3w2 = (const float*)d_in[19];
    const float* m3b2 = (const float*)d_in[20];
    const float* m3w3 = (const float*)d_in[21];
    const float* m3b3 = (const float*)d_in[22];

    half_t* wfrag = (half_t*)d_ws;   // 266 KB of fragments

    PrepArgs pa;
    int off = 0; size_t hoff = 0; int idx = 0;
    auto add = [&](const float* w, int K, int C, int KS, int NT) {
        pa.d[idx] = PrepDesc{w, wfrag + hoff, K, C, KS, NT, off};
        off += KS*NT;
        hoff += (size_t)KS*NT*512;
        ++idx;
    };
    add(m1w0, 13, 150, 1, 10);          // L0
    add(m1w1, 150, 100, 5, 7);          // L1
    add(m2w0, 100, 100, 4, 7);          // L2
    add(m2w1, 100, 50, 4, 4);           // L3
    add(aw0, 100, 100, 4, 7);           // L4 (rows 0..99)
    add(aw0 + 100*100, 100, 100, 4, 7); // L5 (rows 100..199)
    add(aw1, 100, 100, 4, 7);           // L6
    add(aw2, 100, 1, 4, 1);             // L7
    add(m3w0, 56, 150, 2, 10);          // L8
    add(m3w1, 150, 100, 5, 7);          // L9
    add(m3w2, 100, 100, 4, 7);          // L10

    k_prep<<<off, 64, 0, stream>>>(pa);

    k_main<<<NELEM/4, 512, 0, stream>>>(state, wfrag,
        m1b0, m1b1, m2b0, m2b1, ab0, ab1, ab2,
        m3b0, m3b1, m3b2, m3w3, m3b3, (float*)d_out);
}

// Round 6
// 231.068 us; speedup vs baseline: 1.3036x; 1.0079x over previous
//
#include <hip/hip_runtime.h>

typedef _Float16 half_t;
typedef _Float16 half8 __attribute__((ext_vector_type(8)));
typedef float f32x4 __attribute__((ext_vector_type(4)));

#define NELEM 16384
#define SROW 168   // LDS row stride in halves (dword stride 84 == 20 mod 32: conflict-free-ish)

// ---------------------------------------------------------------------------
// In-wave fused network. Wave = 2 elements (40 rows -> 3 M-tiles of 16).
// No __syncthreads anywhere: each wave owns a private 48x168 fp16 LDS buffer,
// layers run in-place (A-fragments are pulled into registers BEFORE the
// epilogue overwrites the buffer; LDS ops of one wave execute in order).
//   B (weights): global pre-swizzled frags [ks][nt][lane][8] (fp16).
//   Layouts (verified): A[m=lane&15][k=quad*8+j], B[k][n=lane&15],
//                       D[row=quad*4+r][col=lane&15].
// ---------------------------------------------------------------------------

template<int KS, int MT>
__device__ __forceinline__ void load_af(half8 (&af)[KS][MT], const half_t* S, int m, int q) {
    #pragma unroll
    for (int ks = 0; ks < KS; ++ks)
        #pragma unroll
        for (int t = 0; t < MT; ++t)
            af[ks][t] = *(const half8*)(S + (t*16 + m)*SROW + q*8 + ks*32);
}

// EPI: 0 = f16 store cols [0,NT*16) (pad cols get 0);  1 = f16 store at col
// offset 112, col<56 (the f vector);  2 = logits -> lbufw[row] (m==0);
// 3 = gp -> gpb[row*112+col] fp32, row<2.   INIT==1: add gpb[(row/20)*112+col].
template<int KS, int MT, int NT, int C, int EPI, int INIT, bool RELU>
__device__ __forceinline__ void run_layer(
    const half8 (&af)[KS][MT], half_t* S,
    const half_t* __restrict__ wf, const float* __restrict__ bias,
    float* gpb, float* lbufw, float extra, int lane)
{
    const int m = lane & 15, q = lane >> 4;
    #pragma unroll
    for (int nt = 0; nt < NT; ++nt) {
        const int col = nt*16 + m;
        half8 bh[KS];
        #pragma unroll
        for (int ks = 0; ks < KS; ++ks)
            bh[ks] = *(const half8*)(wf + ((size_t)(ks*NT + nt)*64 + lane)*8);
        f32x4 acc[MT];
        #pragma unroll
        for (int t = 0; t < MT; ++t) acc[t] = f32x4{0.f,0.f,0.f,0.f};
        #pragma unroll
        for (int ks = 0; ks < KS; ++ks)
            #pragma unroll
            for (int t = 0; t < MT; ++t)
                acc[t] = __builtin_amdgcn_mfma_f32_16x16x32_f16(af[ks][t], bh[ks], acc[t], 0,0,0);
        float bv = 0.f;
        if (EPI == 0 || EPI == 1) bv = (col < C) ? bias[col] : 0.f;
        #pragma unroll
        for (int t = 0; t < MT; ++t) {
            #pragma unroll
            for (int r = 0; r < 4; ++r) {
                const int row = t*16 + q*4 + r;
                float v = acc[t][r] + bv;
                if (INIT == 1) v += gpb[(row/20)*112 + col];  // pad rows read junk; relu+discard
                if (RELU) v = fmaxf(v, 0.f);
                if (EPI == 0) {
                    S[row*SROW + col] = (half_t)v;
                } else if (EPI == 1) {
                    if (col < 56) S[row*SROW + 112 + col] = (half_t)v;
                } else if (EPI == 2) {
                    if (m == 0) lbufw[row] = v + extra;
                } else if (EPI == 3) {
                    if (row < 2) gpb[row*112 + col] = v;
                }
            }
        }
    }
}

// ---------------------------------------------------------------------------
// Prep: build fp16 weight fragments in ws. One 16x32 tile per block.
// ---------------------------------------------------------------------------
struct PrepDesc { const float* w; half_t* out; int K, C, KS, NT, toff; };
struct PrepArgs { PrepDesc d[11]; };

__global__ __launch_bounds__(64) void k_prep(PrepArgs a) {
    const int blk = blockIdx.x, lane = threadIdx.x;
    int li = 0;
    #pragma unroll
    for (int i = 1; i < 11; ++i) if (blk >= a.d[i].toff) li = i;
    const PrepDesc d = a.d[li];
    const int t = blk - d.toff;
    const int ks = t / d.NT, nt = t - (t / d.NT) * d.NT;
    const int c = nt*16 + (lane & 15);
    half_t* o = d.out + ((size_t)(ks*d.NT + nt))*512 + lane*8;
    #pragma unroll
    for (int j = 0; j < 8; ++j) {
        const int k = ks*32 + (lane >> 4)*8 + j;
        float v = (k < d.K && c < d.C) ? d.w[(size_t)k*d.C + c] : 0.f;
        o[j] = (half_t)v;
    }
}

// ---------------------------------------------------------------------------
// k_main: 256 threads = 4 independent waves, 2 elements each. Barrier-free.
// ---------------------------------------------------------------------------
__global__ __launch_bounds__(256, 2) void k_main(
    const float* __restrict__ state,
    const half_t* __restrict__ wfrag,
    const float* __restrict__ m1b0, const float* __restrict__ m1b1,
    const float* __restrict__ m2b0, const float* __restrict__ m2b1,
    const float* __restrict__ ab0, const float* __restrict__ ab1,
    const float* __restrict__ ab2,
    const float* __restrict__ m3b0, const float* __restrict__ m3b1,
    const float* __restrict__ m3b2,
    const float* __restrict__ m3w3, const float* __restrict__ m3b3,
    float* __restrict__ out)
{
    __shared__ __align__(16) half_t S_all[4][48*SROW];
    __shared__ float gp_all[4][2*112];
    __shared__ float lb_all[4][48];

    const int tid = threadIdx.x;
    const int wv = tid >> 6, lane = tid & 63;
    const int m = lane & 15, q = lane >> 4;
    half_t* S = S_all[wv];
    float* gpb = gp_all[wv];
    float* lbufw = lb_all[wv];
    const int ebase = blockIdx.x * 8 + wv * 2;

    const half_t* wfL0 = wfrag;
    const half_t* wfL1 = wfL0 + 5120;
    const half_t* wfL2 = wfL1 + 17920;
    const half_t* wfL3 = wfL2 + 14336;
    const half_t* wfL4 = wfL3 + 8192;
    const half_t* wfL5 = wfL4 + 14336;
    const half_t* wfL6 = wfL5 + 14336;
    const half_t* wfL7 = wfL6 + 14336;
    const half_t* wfL8 = wfL7 + 2048;
    const half_t* wfL9 = wfL8 + 10240;
    const half_t* wfL10 = wfL9 + 17920;

    // ---- stage x: rows 0..47 x cols 0..32 (zero-padded); zero strip cols 112..128
    {
        const float* xg = state + (size_t)ebase * 20 * 13;
        for (int u = lane; u < 48*32; u += 64) {
            const int r = u >> 5, c = u & 31;
            float v = (r < 40 && c < 13) ? xg[r*13 + c] : 0.f;
            S[r*SROW + c] = (half_t)v;
        }
        for (int u = lane; u < 48*16; u += 64)
            S[(u >> 4)*SROW + 112 + (u & 15)] = (half_t)0.f;
    }

    // ---- L0: h1 = relu(x @ m1w0 + b), in-place (x -> cols 0..160)
    {
        half8 af[1][3]; load_af<1,3>(af, S, m, q);
        run_layer<1,3,10,150,0,0,true>(af, S, wfL0, m1b0, gpb, lbufw, 0.f, lane);
    }
    // ---- L1: h = relu(h1 @ m1w1 + b)  (cols 0..112)
    {
        half8 af[5][3]; load_af<5,3>(af, S, m, q);
        run_layer<5,3,7,100,0,0,true>(af, S, wfL1, m1b1, gpb, lbufw, 0.f, lane);
    }
    // ---- keep h fragments in registers (serves L2 and L4); k-pad cols 112..128 are zero
    half8 hf[4][3]; load_af<4,3>(hf, S, m, q);

    // ---- g = mean_n h  -> strips at cols 112..168 (rows 2e+c/56), fp16
    for (int u = lane; u < 224; u += 64) {
        const int e = u / 112, c = u - e*112;
        float s = 0.f;
        if (c < 100) {
            #pragma unroll
            for (int n = 0; n < 20; ++n) s += (float)S[(e*20+n)*SROW + c];
            s *= 0.05f;
        }
        const int st = c / 56;
        S[(2*e + st)*SROW + 112 + (c - st*56)] = (half_t)s;
    }
    // ---- gp = g @ aw0[100:]  (16-row tile; rows>=2 junk, discarded by guard)
    {
        half8 gaf[4][1];
        #pragma unroll
        for (int ks = 0; ks < 4; ++ks) {
            const int c = q*8 + ks*32;
            const int s = (c >= 112) ? 2 : (c >= 56 ? 1 : 0);
            gaf[ks][0] = *(const half8*)(S + (2*m + s)*SROW + 112 + (c - s*56));
        }
        run_layer<4,1,7,100,3,0,false>(gaf, S, wfL5, nullptr, gpb, lbufw, 0.f, lane);
    }
    // ---- L2: fh = relu(h @ m2w0 + b)  (h from regs; cols 0..112 overwritten)
    run_layer<4,3,7,100,0,0,true>(hf, S, wfL2, m2b0, gpb, lbufw, 0.f, lane);
    // ---- L3: f = fh @ m2w1 + b  -> cols 112..168 (f16, no relu)
    {
        half8 af[4][3]; load_af<4,3>(af, S, m, q);
        run_layer<4,3,4,50,1,0,false>(af, S, wfL3, m2b1, gpb, lbufw, 0.f, lane);
    }
    // ---- L4: a1 = relu(h @ aw0[:100] + gp + ab0)  (h from regs; cols 0..112)
    run_layer<4,3,7,100,0,1,true>(hf, S, wfL4, ab0, gpb, lbufw, 0.f, lane);
    // ---- L6: a2 = relu(a1 @ aw1 + ab1)  in-place
    {
        half8 af[4][3]; load_af<4,3>(af, S, m, q);
        run_layer<4,3,7,100,0,0,true>(af, S, wfL6, ab1, gpb, lbufw, 0.f, lane);
    }
    // ---- L7: logits = a2 @ aw2 + ab2 -> lbufw
    {
        half8 af[4][3]; load_af<4,3>(af, S, m, q);
        run_layer<4,3,1,1,2,0,false>(af, S, wfL7, nullptr, gpb, lbufw, ab2[0], lane);
    }
    // ---- weighted + self -> joint tile (rows 0..15, cols 0..64) ----
    {
        float jv[2];
        #pragma unroll
        for (int z = 0; z < 2; ++z) {
            const int u = lane + z*64;
            float v = 0.f;
            if (u < 100) {
                const int e = u / 50, j = u - e*50;
                #pragma unroll
                for (int n = 0; n < 20; ++n)
                    v += (float)S[(e*20+n)*SROW + 112 + j] * lbufw[e*20+n];
            } else if (u < 112) {
                const int d = u - 100; const int e = d / 6, dd = d - e*6;
                v = state[(size_t)(ebase + e)*260 + dd];
            }
            jv[z] = v;
        }
        for (int u = lane; u < 16*64; u += 64)
            S[(u >> 6)*SROW + (u & 63)] = (half_t)0.f;
        #pragma unroll
        for (int z = 0; z < 2; ++z) {
            const int u = lane + z*64;
            if (u < 100) {
                const int e = u / 50, j = u - e*50;
                S[e*SROW + 6 + j] = (half_t)jv[z];
            } else if (u < 112) {
                const int d = u - 100; const int e = d / 6, dd = d - e*6;
                S[e*SROW + dd] = (half_t)jv[z];
            }
        }
    }
    // ---- head: v1 = relu(joint @ m3w0 + b0)  (rows 0..15, cols 0..160)
    {
        half8 af[2][1]; load_af<2,1>(af, S, m, q);
        run_layer<2,1,10,150,0,0,true>(af, S, wfL8, m3b0, gpb, lbufw, 0.f, lane);
    }
    // ---- v2 = relu(v1 @ m3w1 + b1)
    {
        half8 af[5][1]; load_af<5,1>(af, S, m, q);
        run_layer<5,1,7,100,0,0,true>(af, S, wfL9, m3b1, gpb, lbufw, 0.f, lane);
    }
    // ---- v3 = relu(v2 @ m3w2 + b2)
    {
        half8 af[4][1]; load_af<4,1>(af, S, m, q);
        run_layer<4,1,7,100,0,0,true>(af, S, wfL10, m3b2, gpb, lbufw, 0.f, lane);
    }
    // ---- out[e] = v3[e] . m3w3 + b3   (lanes 0-31 -> elem 0, 32-63 -> elem 1)
    {
        const int e = lane >> 5, k = lane & 31;
        const half_t* vr = S + e*SROW;
        float s = (float)vr[k]      * m3w3[k]
                + (float)vr[k + 32] * m3w3[k + 32]
                + (float)vr[k + 64] * m3w3[k + 64];
        if (k < 4) s += (float)vr[k + 96] * m3w3[k + 96];
        #pragma unroll
        for (int off = 16; off > 0; off >>= 1)
            s += __shfl_down(s, off, 32);
        if (k == 0) out[ebase + e] = s + m3b3[0];
    }
}

extern "C" void kernel_launch(void* const* d_in, const int* in_sizes, int n_in,
                              void* d_out, int out_size, void* d_ws, size_t ws_size,
                              hipStream_t stream) {
    const float* state = (const float*)d_in[0];
    const float* m1w0 = (const float*)d_in[1];
    const float* m1b0 = (const float*)d_in[2];
    const float* m1w1 = (const float*)d_in[3];
    const float* m1b1 = (const float*)d_in[4];
    const float* m2w0 = (const float*)d_in[5];
    const float* m2b0 = (const float*)d_in[6];
    const float* m2w1 = (const float*)d_in[7];
    const float* m2b1 = (const float*)d_in[8];
    const float* aw0  = (const float*)d_in[9];
    const float* ab0  = (const float*)d_in[10];
    const float* aw1  = (const float*)d_in[11];
    const float* ab1  = (const float*)d_in[12];
    const float* aw2  = (const float*)d_in[13];
    const float* ab2  = (const float*)d_in[14];
    const float* m3w0 = (const float*)d_in[15];
    const float* m3b0 = (const float*)d_in[16];
    const float* m3w1 = (const float*)d_in[17];
    const float* m3b1 = (const float*)d_in[18];
    const float* m3w2 = (const float*)d_in[19];
    const float* m3b2 = (const float*)d_in[20];
    const float* m3w3 = (const float*)d_in[21];
    const float* m3b3 = (const float*)d_in[22];

    half_t* wfrag = (half_t*)d_ws;   // 266 KB of fragments

    PrepArgs pa;
    int off = 0; size_t hoff = 0; int idx = 0;
    auto add = [&](const float* w, int K, int C, int KS, int NT) {
        pa.d[idx] = PrepDesc{w, wfrag + hoff, K, C, KS, NT, off};
        off += KS*NT;
        hoff += (size_t)KS*NT*512;
        ++idx;
    };
    add(m1w0, 13, 150, 1, 10);          // L0
    add(m1w1, 150, 100, 5, 7);          // L1
    add(m2w0, 100, 100, 4, 7);          // L2
    add(m2w1, 100, 50, 4, 4);           // L3
    add(aw0, 100, 100, 4, 7);           // L4 (rows 0..99)
    add(aw0 + 100*100, 100, 100, 4, 7); // L5 (rows 100..199)
    add(aw1, 100, 100, 4, 7);           // L6
    add(aw2, 100, 1, 4, 1);             // L7
    add(m3w0, 56, 150, 2, 10);          // L8
    add(m3w1, 150, 100, 5, 7);          // L9
    add(m3w2, 100, 100, 4, 7);          // L10

    k_prep<<<off, 64, 0, stream>>>(pa);

    k_main<<<NELEM/8, 256, 0, stream>>>(state, wfrag,
        m1b0, m1b1, m2b0, m2b1, ab0, ab1, ab2,
        m3b0, m3b1, m3b2, m3w3, m3b3, (float*)d_out);
}